// Round 1
// baseline (610.290 us; speedup 1.0000x reference)
//
#include <hip/hip_runtime.h>
#include <hip/hip_bf16.h>
#include <math.h>

// Problem constants
#define SEQ 4096
#define DM  1024
#define NIMU 72
#define NNOISE 12
#define NJ (NIMU*NNOISE)     // 864
#define TSTEPS 300
#define PLANE (NIMU*SEQ)     // 294912

// Fragment-linear layouts (16x16x32 bf16 MFMA operand granules):
//   granule(tile, ch) = 512 shorts; lane l holds 8 shorts at +l*8:
//     row = l&15 (m or n), k = ch*32 + (l>>4)*8 + 0..7
//   ch 0..31 = hi half (k 0..1023), ch 32..63 = lo half.
// A2f : 256 s_tiles x 64 ch x 512 shorts = 16.78 MB
// Btf : 56  j_tiles x 64 ch x 512 shorts =  3.67 MB (j_tiles 54,55 unwritten junk)
// pt  : 864 x 4096 f32 = 14.16 MB
#define A2F_SHORTS ((size_t)256 * 64 * 512)
#define BTF_SHORTS ((size_t)56 * 64 * 512)

typedef __attribute__((ext_vector_type(8))) short bf16x8;
typedef __attribute__((ext_vector_type(4))) float f32x4;
typedef __attribute__((ext_vector_type(2))) float f32x2;

__device__ __forceinline__ float softplus_f(float x) {
    return fmaxf(x, 0.f) + log1pf(expf(-fabsf(x)));
}

// round-to-nearest-even bf16 split: x ~= hi + lo with |err| ~ 2^-16 * |x|
__device__ __forceinline__ void split_bf16(float x, short& hi, short& lo) {
    unsigned b = __float_as_uint(x);
    unsigned h = (b + 0x7FFFu + ((b >> 16) & 1u)) >> 16;
    float hf = __uint_as_float(h << 16);
    float r = x - hf;
    unsigned b2 = __float_as_uint(r);
    unsigned l2 = (b2 + 0x7FFFu + ((b2 >> 16) & 1u)) >> 16;
    hi = (short)h;
    lo = (short)l2;
}

// ---------------- 1. LayerNorm -> A2f (fragment-linear bf16 hi|lo) ----------------
__global__ __launch_bounds__(256) void ln_kernel(const float* __restrict__ x,
                                                 const float* __restrict__ gamma,
                                                 const float* __restrict__ beta,
                                                 short* __restrict__ A2f) {
    const int s_tile = blockIdx.x;
    const int tid = threadIdx.x;
    const int mrow = tid >> 4;      // row within s_tile
    const int g    = tid & 15;
    const int row  = s_tile * 16 + mrow;
    const float4* xr = (const float4*)(x + (size_t)row * DM);

    float s = 0.f, sq = 0.f;
    #pragma unroll
    for (int i = 0; i < 16; ++i) {
        float4 v = xr[g + 16 * i];
        s  += v.x + v.y + v.z + v.w;
        sq += v.x*v.x + v.y*v.y + v.z*v.z + v.w*v.w;
    }
    #pragma unroll
    for (int off = 1; off < 16; off <<= 1) {
        s  += __shfl_xor(s, off);
        sq += __shfl_xor(sq, off);
    }
    const float mean = s * (1.f / DM);
    const float var  = sq * (1.f / DM) - mean * mean;
    const float rstd = rsqrtf(fmaxf(var, 0.f) + 1e-5f);

    #pragma unroll
    for (int i = 0; i < 16; ++i) {
        float4 v = xr[g + 16 * i];
        float4 gm = ((const float4*)gamma)[g + 16 * i];
        float4 bt = ((const float4*)beta)[g + 16 * i];
        float o[4];
        o[0] = (v.x - mean) * rstd * gm.x + bt.x;
        o[1] = (v.y - mean) * rstd * gm.y + bt.y;
        o[2] = (v.z - mean) * rstd * gm.z + bt.z;
        o[3] = (v.w - mean) * rstd * gm.w + bt.w;
        short4 hv, lv;
        split_bf16(o[0], hv.x, lv.x);
        split_bf16(o[1], hv.y, lv.y);
        split_bf16(o[2], hv.z, lv.z);
        split_bf16(o[3], hv.w, lv.w);
        const int ch = (g >> 3) + 2 * i;
        const size_t base = ((size_t)s_tile * 64 + ch) * 512
                          + mrow * 8 + ((g >> 1) & 3) * 128 + (g & 1) * 4;
        *(short4*)(A2f + base)             = hv;   // hi: ch
        *(short4*)(A2f + base + 32 * 512)  = lv;   // lo: ch+32
    }
}

// ---------------- 2a. W -> Btf (transpose + split, fragment-linear) ----------------
__global__ __launch_bounds__(256) void wprep_kernel(const float* __restrict__ W,
                                                    short* __restrict__ Btf) {
    __shared__ float T[32][33];
    const int k0 = blockIdx.x * 32, j0 = blockIdx.y * 32;
    const int t = threadIdx.x;
    {
        const int r = t >> 3, c4 = (t & 7) * 4;
        float4 v = *(const float4*)(W + (size_t)(k0 + r) * NJ + j0 + c4);
        T[r][c4 + 0] = v.x; T[r][c4 + 1] = v.y; T[r][c4 + 2] = v.z; T[r][c4 + 3] = v.w;
    }
    __syncthreads();
    if (t < 128) {
        const int gq = t >> 6;          // which 16-j group
        const int l  = t & 63;
        const int n = l & 15, c = l >> 4;
        const int jt = blockIdx.y * 2 + gq;       // j_tile
        bf16x8 hv, lv;
        #pragma unroll
        for (int o = 0; o < 8; ++o) {
            short h, lo_;
            split_bf16(T[c * 8 + o][gq * 16 + n], h, lo_);
            hv[o] = h; lv[o] = lo_;
        }
        short* dh = Btf + ((size_t)jt * 64 + blockIdx.x) * 512 + l * 8;
        *(bf16x8*)dh = hv;
        *(bf16x8*)(dh + (size_t)32 * 512) = lv;   // lo chunk = ch+32
    }
}

// ---------------- 2b. Barrier-free MFMA GEMM: pt[j,s] = ((xn @ W)^T + b) ----------------
__global__ __launch_bounds__(256, 1) void gemm_kernel(const short* __restrict__ A2f,
                                                      const short* __restrict__ Btf,
                                                      const float* __restrict__ bias,
                                                      float* __restrict__ pt) {
    const int l = threadIdx.x & 63, w = threadIdx.x >> 6;
    const int st0 = blockIdx.x * 8 + (w & 1) * 4;    // wave's m-tile base
    const int jt0 = blockIdx.y * 8 + (w >> 1) * 4;   // wave's n-tile base
    const short* aB = A2f + (size_t)st0 * (64 * 512) + l * 8;
    const short* bB = Btf + (size_t)jt0 * (64 * 512) + l * 8;

    f32x4 acc[4][4] = {};
    bf16x8 ah[2][4], al[2][4], bh[2][4], bl[2][4];

    auto ldstep = [&](int slot, int i) {
        #pragma unroll
        for (int t = 0; t < 4; ++t) {
            ah[slot][t] = *(const bf16x8*)(aB + ((size_t)t * 64 + i) * 512);
            al[slot][t] = *(const bf16x8*)(aB + ((size_t)t * 64 + 32 + i) * 512);
            bh[slot][t] = *(const bf16x8*)(bB + ((size_t)t * 64 + i) * 512);
            bl[slot][t] = *(const bf16x8*)(bB + ((size_t)t * 64 + 32 + i) * 512);
        }
    };

    ldstep(0, 0);
    #pragma unroll 2
    for (int i = 0; i < 32; ++i) {
        const int cur = i & 1;
        if (i + 1 < 32) ldstep(cur ^ 1, i + 1);   // loads in flight during MFMA
        #pragma unroll
        for (int mi = 0; mi < 4; ++mi)
            #pragma unroll
            for (int ni = 0; ni < 4; ++ni)
                acc[mi][ni] = __builtin_amdgcn_mfma_f32_16x16x32_bf16(
                    ah[cur][mi], bh[cur][ni], acc[mi][ni], 0, 0, 0);
        #pragma unroll
        for (int mi = 0; mi < 4; ++mi)
            #pragma unroll
            for (int ni = 0; ni < 4; ++ni)
                acc[mi][ni] = __builtin_amdgcn_mfma_f32_16x16x32_bf16(
                    ah[cur][mi], bl[cur][ni], acc[mi][ni], 0, 0, 0);
        #pragma unroll
        for (int mi = 0; mi < 4; ++mi)
            #pragma unroll
            for (int ni = 0; ni < 4; ++ni)
                acc[mi][ni] = __builtin_amdgcn_mfma_f32_16x16x32_bf16(
                    al[cur][mi], bh[cur][ni], acc[mi][ni], 0, 0, 0);
    }

    // epilogue: C/D layout col=lane&15 (j-within-tile), row=(lane>>4)*4+reg (s)
    const int srow = (l >> 4) * 4;
    const int jcol = l & 15;
    #pragma unroll
    for (int ni = 0; ni < 4; ++ni) {
        const int j = (jt0 + ni) * 16 + jcol;
        if (j < NJ) {
            const float bj = bias[j];
            #pragma unroll
            for (int mi = 0; mi < 4; ++mi) {
                f32x4 v = acc[mi][ni];
                v[0] += bj; v[1] += bj; v[2] += bj; v[3] += bj;
                *(f32x4*)(pt + (size_t)j * SEQ + (st0 + mi) * 16 + srow) = v;
            }
        }
    }
}

// ---------------- 3. Spring recurrence + LDS-window diagonal scatter ----------------
// R8: 52us @ VALUBusy 77% — ~35 VALU instrs per oscillator step; only ~5 are the
// rotation advance. The rest was scatter plumbing: per-step shfl addr math, dual
// predicated accumulates (register-window wrap), runtime tr0 loop, tail branch,
// and the t-split's duplicated transcendental prologue.
// R9: LDS-window scatter. Block = 256 s-values x 1 imu; 555-float LDS window
// accumulates kin[s0 .. s0+554] via ds_add_f32 (DS pipe, stride-1 lanes = 2/bank).
// Per step: 1 extract add + 1 ds_add + packed rotation (~4 VALU). No shfl, no
// predication (masking moves to the flush: pos >= SEQ slots simply not flushed).
// t-split dropped: per-wave issue time (~12cyc/step) already covers the 8cyc
// dependent rotation chain; halves prologue transcendentals + flush atomics.
__global__ __launch_bounds__(256) void spring_kernel(const float* __restrict__ pt,
                                                     float* __restrict__ kin) {
    __shared__ float win[560];                 // 555 used: 256 s + 299 spill
    const int tid = threadIdx.x;
    const int s0  = blockIdx.x * 256;
    const int imu = blockIdx.y;
    const int s   = s0 + tid;

    #pragma unroll
    for (int i = tid; i < 555; i += 256) win[i] = 0.f;

    const int base = imu * SEQ + s;
    const float p0  = pt[(size_t)0 * PLANE + base];
    const float p1  = pt[(size_t)1 * PLANE + base];
    const float p2  = pt[(size_t)2 * PLANE + base];
    const float p3  = pt[(size_t)3 * PLANE + base];
    const float c1  = pt[(size_t)4 * PLANE + base];
    const float c2  = pt[(size_t)5 * PLANE + base];
    const float ph1 = pt[(size_t)6 * PLANE + base];
    const float ph2 = pt[(size_t)7 * PLANE + base];

    float dd = softplus_f(p1);
    float kk = dd * dd * 0.25f + softplus_f(p0);
    float om1 = 0.5f * sqrtf(fmaxf(4.f * kk - dd * dd, 0.f));
    float dt = softplus_f(p3);
    float kt = dt * dt * 0.25f + softplus_f(p2);
    float om2 = 0.5f * sqrtf(fmaxf(4.f * kt - dt * dt, 0.f));
    float e1 = expf(-0.5f * dd), e2 = expf(-0.5f * dt);
    float sn, cs, sn2, cs2;
    sincosf(om1, &sn, &cs);
    sincosf(om2, &sn2, &cs2);
    f32x2 Rr = {e1 * cs, e2 * cs2};          // per-step rotation (packed: osc1, osc2)
    f32x2 Ri = {e1 * sn, e2 * sn2};
    sincosf(ph1, &sn, &cs);
    sincosf(ph2, &sn2, &cs2);
    f32x2 zr = {c1 * cs, c2 * cs2};          // state (packed)
    f32x2 zi = {c1 * sn, c2 * sn2};

    __syncthreads();                          // window zeroed before any ds_add

    float* wp = &win[tid];
    #pragma unroll 10
    for (int t = 0; t < TSTEPS; ++t) {
        const float val = zi.x + zi.y;        // value at step t (extract BEFORE advance)
        (void)__hip_atomic_fetch_add(wp + t, val,
                                     __ATOMIC_RELAXED, __HIP_MEMORY_SCOPE_WORKGROUP);
        f32x2 nr = zr * Rr - zi * Ri;
        zi = zr * Ri + zi * Rr;
        zr = nr;
    }

    __syncthreads();
    // flush: window slot i holds position s0+i; mask = skip pos >= SEQ
    for (int i = tid; i < 555; i += 256) {
        const int pos = s0 + i;
        if (pos < SEQ) {
            (void)__hip_atomic_fetch_add(&kin[(size_t)imu * SEQ + pos], win[i],
                                         __ATOMIC_RELAXED, __HIP_MEMORY_SCOPE_AGENT);
        }
    }
}

// ---------------- 4. acc/gyro base & std outputs ----------------
__global__ __launch_bounds__(256) void tail_kernel(const float* __restrict__ pt,
                                                   float* __restrict__ out) {
    int idx = blockIdx.x * 256 + threadIdx.x;
    if (idx >= 4 * PLANE) return;
    float v = pt[(size_t)8 * PLANE + idx];
    int q = idx / PLANE;
    if (q & 1) v = softplus_f(v);
    out[(size_t)PLANE + idx] = v;
}

extern "C" void kernel_launch(void* const* d_in, const int* in_sizes, int n_in,
                              void* d_out, int out_size, void* d_ws, size_t ws_size,
                              hipStream_t stream) {
    const float* hs    = (const float*)d_in[0];
    const float* gamma = (const float*)d_in[1];
    const float* beta  = (const float*)d_in[2];
    const float* W     = (const float*)d_in[3];
    const float* b     = (const float*)d_in[4];
    float* out = (float*)d_out;

    short* A2f = (short*)d_ws;                        // 16.78 MB
    short* Btf = A2f + A2F_SHORTS;                    //  3.67 MB
    float* pt  = (float*)(Btf + BTF_SHORTS);          // 14.16 MB

    hipMemsetAsync(out, 0, (size_t)PLANE * sizeof(float), stream);

    ln_kernel<<<SEQ / 16, 256, 0, stream>>>(hs, gamma, beta, A2f);
    wprep_kernel<<<dim3(DM / 32, NJ / 32), 256, 0, stream>>>(W, Btf);
    gemm_kernel<<<dim3(SEQ / 128, 7), 256, 0, stream>>>(A2f, Btf, b, pt);
    spring_kernel<<<dim3(SEQ / 256, NIMU), 256, 0, stream>>>(pt, out);
    tail_kernel<<<(4 * PLANE + 255) / 256, 256, 0, stream>>>(pt, out);
}

// Round 2
// 146.371 us; speedup vs baseline: 4.1695x; 4.1695x over previous
//
#include <hip/hip_runtime.h>
#include <hip/hip_bf16.h>
#include <math.h>

// Problem constants
#define SEQ 4096
#define DM  1024
#define NIMU 72
#define NNOISE 12
#define NJ (NIMU*NNOISE)     // 864
#define TSTEPS 300
#define PLANE (NIMU*SEQ)     // 294912

// Fragment-linear layouts (16x16x32 bf16 MFMA operand granules):
//   granule(tile, ch) = 512 shorts; lane l holds 8 shorts at +l*8:
//     row = l&15 (m or n), k = ch*32 + (l>>4)*8 + 0..7
//   ch 0..31 = hi half (k 0..1023), ch 32..63 = lo half.
// A2f : 256 s_tiles x 64 ch x 512 shorts = 16.78 MB
// Btf : 56  j_tiles x 64 ch x 512 shorts =  3.67 MB (j_tiles 54,55 unwritten junk)
// pt  : 864 x 4096 f32 = 14.16 MB
#define A2F_SHORTS ((size_t)256 * 64 * 512)
#define BTF_SHORTS ((size_t)56 * 64 * 512)

typedef __attribute__((ext_vector_type(8))) short bf16x8;
typedef __attribute__((ext_vector_type(4))) float f32x4;
typedef __attribute__((ext_vector_type(2))) float f32x2;

__device__ __forceinline__ float softplus_f(float x) {
    return fmaxf(x, 0.f) + log1pf(expf(-fabsf(x)));
}

// round-to-nearest-even bf16 split: x ~= hi + lo with |err| ~ 2^-16 * |x|
__device__ __forceinline__ void split_bf16(float x, short& hi, short& lo) {
    unsigned b = __float_as_uint(x);
    unsigned h = (b + 0x7FFFu + ((b >> 16) & 1u)) >> 16;
    float hf = __uint_as_float(h << 16);
    float r = x - hf;
    unsigned b2 = __float_as_uint(r);
    unsigned l2 = (b2 + 0x7FFFu + ((b2 >> 16) & 1u)) >> 16;
    hi = (short)h;
    lo = (short)l2;
}

// ---------------- 1. LayerNorm -> A2f (fragment-linear bf16 hi|lo) ----------------
__global__ __launch_bounds__(256) void ln_kernel(const float* __restrict__ x,
                                                 const float* __restrict__ gamma,
                                                 const float* __restrict__ beta,
                                                 short* __restrict__ A2f) {
    const int s_tile = blockIdx.x;
    const int tid = threadIdx.x;
    const int mrow = tid >> 4;      // row within s_tile
    const int g    = tid & 15;
    const int row  = s_tile * 16 + mrow;
    const float4* xr = (const float4*)(x + (size_t)row * DM);

    float s = 0.f, sq = 0.f;
    #pragma unroll
    for (int i = 0; i < 16; ++i) {
        float4 v = xr[g + 16 * i];
        s  += v.x + v.y + v.z + v.w;
        sq += v.x*v.x + v.y*v.y + v.z*v.z + v.w*v.w;
    }
    #pragma unroll
    for (int off = 1; off < 16; off <<= 1) {
        s  += __shfl_xor(s, off);
        sq += __shfl_xor(sq, off);
    }
    const float mean = s * (1.f / DM);
    const float var  = sq * (1.f / DM) - mean * mean;
    const float rstd = rsqrtf(fmaxf(var, 0.f) + 1e-5f);

    #pragma unroll
    for (int i = 0; i < 16; ++i) {
        float4 v = xr[g + 16 * i];
        float4 gm = ((const float4*)gamma)[g + 16 * i];
        float4 bt = ((const float4*)beta)[g + 16 * i];
        float o[4];
        o[0] = (v.x - mean) * rstd * gm.x + bt.x;
        o[1] = (v.y - mean) * rstd * gm.y + bt.y;
        o[2] = (v.z - mean) * rstd * gm.z + bt.z;
        o[3] = (v.w - mean) * rstd * gm.w + bt.w;
        short4 hv, lv;
        split_bf16(o[0], hv.x, lv.x);
        split_bf16(o[1], hv.y, lv.y);
        split_bf16(o[2], hv.z, lv.z);
        split_bf16(o[3], hv.w, lv.w);
        const int ch = (g >> 3) + 2 * i;
        const size_t base = ((size_t)s_tile * 64 + ch) * 512
                          + mrow * 8 + ((g >> 1) & 3) * 128 + (g & 1) * 4;
        *(short4*)(A2f + base)             = hv;   // hi: ch
        *(short4*)(A2f + base + 32 * 512)  = lv;   // lo: ch+32
    }
}

// ---------------- 2a. W -> Btf (transpose + split, fragment-linear) ----------------
__global__ __launch_bounds__(256) void wprep_kernel(const float* __restrict__ W,
                                                    short* __restrict__ Btf) {
    __shared__ float T[32][33];
    const int k0 = blockIdx.x * 32, j0 = blockIdx.y * 32;
    const int t = threadIdx.x;
    {
        const int r = t >> 3, c4 = (t & 7) * 4;
        float4 v = *(const float4*)(W + (size_t)(k0 + r) * NJ + j0 + c4);
        T[r][c4 + 0] = v.x; T[r][c4 + 1] = v.y; T[r][c4 + 2] = v.z; T[r][c4 + 3] = v.w;
    }
    __syncthreads();
    if (t < 128) {
        const int gq = t >> 6;          // which 16-j group
        const int l  = t & 63;
        const int n = l & 15, c = l >> 4;
        const int jt = blockIdx.y * 2 + gq;       // j_tile
        bf16x8 hv, lv;
        #pragma unroll
        for (int o = 0; o < 8; ++o) {
            short h, lo_;
            split_bf16(T[c * 8 + o][gq * 16 + n], h, lo_);
            hv[o] = h; lv[o] = lo_;
        }
        short* dh = Btf + ((size_t)jt * 64 + blockIdx.x) * 512 + l * 8;
        *(bf16x8*)dh = hv;
        *(bf16x8*)(dh + (size_t)32 * 512) = lv;   // lo chunk = ch+32
    }
}

// ---------------- 2b. Barrier-free MFMA GEMM: pt[j,s] = ((xn @ W)^T + b) ----------------
__global__ __launch_bounds__(256, 1) void gemm_kernel(const short* __restrict__ A2f,
                                                      const short* __restrict__ Btf,
                                                      const float* __restrict__ bias,
                                                      float* __restrict__ pt) {
    const int l = threadIdx.x & 63, w = threadIdx.x >> 6;
    const int st0 = blockIdx.x * 8 + (w & 1) * 4;    // wave's m-tile base
    const int jt0 = blockIdx.y * 8 + (w >> 1) * 4;   // wave's n-tile base
    const short* aB = A2f + (size_t)st0 * (64 * 512) + l * 8;
    const short* bB = Btf + (size_t)jt0 * (64 * 512) + l * 8;

    f32x4 acc[4][4] = {};
    bf16x8 ah[2][4], al[2][4], bh[2][4], bl[2][4];

    auto ldstep = [&](int slot, int i) {
        #pragma unroll
        for (int t = 0; t < 4; ++t) {
            ah[slot][t] = *(const bf16x8*)(aB + ((size_t)t * 64 + i) * 512);
            al[slot][t] = *(const bf16x8*)(aB + ((size_t)t * 64 + 32 + i) * 512);
            bh[slot][t] = *(const bf16x8*)(bB + ((size_t)t * 64 + i) * 512);
            bl[slot][t] = *(const bf16x8*)(bB + ((size_t)t * 64 + 32 + i) * 512);
        }
    };

    ldstep(0, 0);
    #pragma unroll 2
    for (int i = 0; i < 32; ++i) {
        const int cur = i & 1;
        if (i + 1 < 32) ldstep(cur ^ 1, i + 1);   // loads in flight during MFMA
        #pragma unroll
        for (int mi = 0; mi < 4; ++mi)
            #pragma unroll
            for (int ni = 0; ni < 4; ++ni)
                acc[mi][ni] = __builtin_amdgcn_mfma_f32_16x16x32_bf16(
                    ah[cur][mi], bh[cur][ni], acc[mi][ni], 0, 0, 0);
        #pragma unroll
        for (int mi = 0; mi < 4; ++mi)
            #pragma unroll
            for (int ni = 0; ni < 4; ++ni)
                acc[mi][ni] = __builtin_amdgcn_mfma_f32_16x16x32_bf16(
                    ah[cur][mi], bl[cur][ni], acc[mi][ni], 0, 0, 0);
        #pragma unroll
        for (int mi = 0; mi < 4; ++mi)
            #pragma unroll
            for (int ni = 0; ni < 4; ++ni)
                acc[mi][ni] = __builtin_amdgcn_mfma_f32_16x16x32_bf16(
                    al[cur][mi], bh[cur][ni], acc[mi][ni], 0, 0, 0);
    }

    // epilogue: C/D layout col=lane&15 (j-within-tile), row=(lane>>4)*4+reg (s)
    const int srow = (l >> 4) * 4;
    const int jcol = l & 15;
    #pragma unroll
    for (int ni = 0; ni < 4; ++ni) {
        const int j = (jt0 + ni) * 16 + jcol;
        if (j < NJ) {
            const float bj = bias[j];
            #pragma unroll
            for (int mi = 0; mi < 4; ++mi) {
                f32x4 v = acc[mi][ni];
                v[0] += bj; v[1] += bj; v[2] += bj; v[3] += bj;
                *(f32x4*)(pt + (size_t)j * SEQ + (st0 + mi) * 16 + srow) = v;
            }
        }
    }
}

// ---------------- 3. Spring recurrence + wave-private LDS-window scatter ----------------
// R8: 52us, VALU-bound (~35 instr/step: shuffle+predication plumbing).
// R9 FAILED (495us): __hip_atomic_fetch_add on LDS pointer -> generic/flat atomic
// path, not ds_add. VALUBusy 3% = serialized long-latency RMW. Lesson: plain
// ds_read/v_add/ds_write only; races avoided structurally, not with atomics.
// R10: wave-PRIVATE windows (4 x 368 floats). At step t lane l RMWs win[l+t] --
// distinct addresses per lane, race-free within a lockstep wave; cross-wave races
// gone by privatization. Two t-streams 150 apart (z_B = z*R^150) share one base
// register with imm offsets (j, j+150 dwords <= 255) so reads/writes fuse into
// ds_read2_b32/ds_write2_b32: 1 DS access per contribution, zero per-step addr
// math. Per macro-step (2 contribs): 2 fused DS + ~11 VALU. Compiler memory
// barrier per step pins write(j) before read(j+1) (cross-lane RAW the optimizer
// could otherwise reorder). Merge 4 windows + masked global-atomic flush.
__global__ __launch_bounds__(256) void spring_kernel(const float* __restrict__ pt,
                                                     float* __restrict__ kin) {
    __shared__ float win[4 * 368];             // 363 used per wave
    const int tid  = threadIdx.x;
    const int lane = tid & 63;
    const int wid  = tid >> 6;
    const int s0   = blockIdx.x * 256;
    const int imu  = blockIdx.y;
    const int s    = s0 + (wid << 6) + lane;

    float* w0 = win + wid * 368;
    // zero own window (wave-private: no barrier needed before main loop)
    #pragma unroll
    for (int i = 0; i < 6; ++i) {
        const int idx = lane + i * 64;
        if (idx < 363) w0[idx] = 0.f;
    }

    const int base = imu * SEQ + s;
    const float p0  = pt[(size_t)0 * PLANE + base];
    const float p1  = pt[(size_t)1 * PLANE + base];
    const float p2  = pt[(size_t)2 * PLANE + base];
    const float p3  = pt[(size_t)3 * PLANE + base];
    const float c1  = pt[(size_t)4 * PLANE + base];
    const float c2  = pt[(size_t)5 * PLANE + base];
    const float ph1 = pt[(size_t)6 * PLANE + base];
    const float ph2 = pt[(size_t)7 * PLANE + base];

    float dd = softplus_f(p1);
    float kk = dd * dd * 0.25f + softplus_f(p0);
    float om1 = 0.5f * sqrtf(fmaxf(4.f * kk - dd * dd, 0.f));
    float dt = softplus_f(p3);
    float kt = dt * dt * 0.25f + softplus_f(p2);
    float om2 = 0.5f * sqrtf(fmaxf(4.f * kt - dt * dt, 0.f));
    float e1 = expf(-0.5f * dd), e2 = expf(-0.5f * dt);
    float sn, cs, sn2, cs2;
    sincosf(om1, &sn, &cs);
    sincosf(om2, &sn2, &cs2);
    f32x2 Rr = {e1 * cs, e2 * cs2};          // per-step rotation (packed: osc1, osc2)
    f32x2 Ri = {e1 * sn, e2 * sn2};
    sincosf(ph1, &sn, &cs);
    sincosf(ph2, &sn2, &cs2);
    f32x2 zr = {c1 * cs, c2 * cs2};          // stream A state (t = 0)
    f32x2 zi = {c1 * sn, c2 * sn2};

    // stream B state: z * R^150 (exp-by-squaring)
    f32x2 zrB, ziB;
    {
        f32x2 prr = Rr, pri = Ri;
        f32x2 qr = {1.f, 1.f}, qi = {0.f, 0.f};
        int e = 150;
        while (e) {
            if (e & 1) {
                f32x2 nr = qr * prr - qi * pri;
                qi = qr * pri + qi * prr;
                qr = nr;
            }
            f32x2 nr = prr * prr - pri * pri;
            pri = 2.f * prr * pri;
            prr = nr;
            e >>= 1;
        }
        f32x2 nr = zr * qr - zi * qi;
        ziB = zr * qi + zi * qr;
        zrB = nr;
    }

    float* wp = w0 + lane;
    // macro-step j covers t = tb+j (stream A) and t = tb+j+150 (stream B)
    #pragma unroll 1
    for (int tb = 0; tb < 128; tb += 32) {
        float* wq = wp + tb;
        #pragma unroll
        for (int j = 0; j < 32; ++j) {
            const float vA = zi.x + zi.y;
            const float vB = ziB.x + ziB.y;
            const float a = wq[j];
            const float b = wq[j + 150];
            wq[j]       = a + vA;
            wq[j + 150] = b + vB;
            f32x2 nr = zr * Rr - zi * Ri;
            zi = zr * Ri + zi * Rr;
            zr = nr;
            nr = zrB * Rr - ziB * Ri;
            ziB = zrB * Ri + ziB * Rr;
            zrB = nr;
            __asm__ volatile("" ::: "memory");   // pin write(j) before read(j+1)
        }
    }
    {   // tail: t = 128..149 (A), 278..299 (B)
        float* wq = wp + 128;
        #pragma unroll
        for (int j = 0; j < 22; ++j) {
            const float vA = zi.x + zi.y;
            const float vB = ziB.x + ziB.y;
            const float a = wq[j];
            const float b = wq[j + 150];
            wq[j]       = a + vA;
            wq[j + 150] = b + vB;
            f32x2 nr = zr * Rr - zi * Ri;
            zi = zr * Ri + zi * Rr;
            zr = nr;
            nr = zrB * Rr - ziB * Ri;
            ziB = zrB * Ri + ziB * Rr;
            zrB = nr;
            __asm__ volatile("" ::: "memory");
        }
    }

    __syncthreads();
    // merge 4 wave windows + masked global flush
    // block output i in [0,555): wave w's window covers [64w, 64w+362]
    for (int i = tid; i < 555; i += 256) {
        float sum = 0.f;
        #pragma unroll
        for (int w = 0; w < 4; ++w) {
            const int idx = i - (w << 6);
            if (idx >= 0 && idx < 363) sum += win[w * 368 + idx];
        }
        const int pos = s0 + i;
        if (pos < SEQ) {
            (void)__hip_atomic_fetch_add(&kin[(size_t)imu * SEQ + pos], sum,
                                         __ATOMIC_RELAXED, __HIP_MEMORY_SCOPE_AGENT);
        }
    }
}

// ---------------- 4. acc/gyro base & std outputs ----------------
__global__ __launch_bounds__(256) void tail_kernel(const float* __restrict__ pt,
                                                   float* __restrict__ out) {
    int idx = blockIdx.x * 256 + threadIdx.x;
    if (idx >= 4 * PLANE) return;
    float v = pt[(size_t)8 * PLANE + idx];
    int q = idx / PLANE;
    if (q & 1) v = softplus_f(v);
    out[(size_t)PLANE + idx] = v;
}

extern "C" void kernel_launch(void* const* d_in, const int* in_sizes, int n_in,
                              void* d_out, int out_size, void* d_ws, size_t ws_size,
                              hipStream_t stream) {
    const float* hs    = (const float*)d_in[0];
    const float* gamma = (const float*)d_in[1];
    const float* beta  = (const float*)d_in[2];
    const float* W     = (const float*)d_in[3];
    const float* b     = (const float*)d_in[4];
    float* out = (float*)d_out;

    short* A2f = (short*)d_ws;                        // 16.78 MB
    short* Btf = A2f + A2F_SHORTS;                    //  3.67 MB
    float* pt  = (float*)(Btf + BTF_SHORTS);          // 14.16 MB

    hipMemsetAsync(out, 0, (size_t)PLANE * sizeof(float), stream);

    ln_kernel<<<SEQ / 16, 256, 0, stream>>>(hs, gamma, beta, A2f);
    wprep_kernel<<<dim3(DM / 32, NJ / 32), 256, 0, stream>>>(W, Btf);
    gemm_kernel<<<dim3(SEQ / 128, 7), 256, 0, stream>>>(A2f, Btf, b, pt);
    spring_kernel<<<dim3(SEQ / 256, NIMU), 256, 0, stream>>>(pt, out);
    tail_kernel<<<(4 * PLANE + 255) / 256, 256, 0, stream>>>(pt, out);
}